// Round 9
// baseline (187.258 us; speedup 1.0000x reference)
//
#include <hip/hip_runtime.h>
#include <math.h>

// Problem constants (fixed by setup_inputs): N src points, M targets, D=3.
constexpr int N_SRC = 16384;
constexpr int M_TAR = 16384;

// ---------------- R9: uniform-grid exact 1-NN ----------------
// Points are N(0,1)^3. Grid 24^3 over [-4,4), h=1/3 (outliers clamped into
// edge cells — safe: a clamped point's true distance >= its cell's lower
// bound, and shell lb(s+1) >= s*h holds from any true query position).
// Loss needs only min EXACT fp32 d2 per target (0.5*bd2 is the term);
// reference near-tie flips cost <= its expansion rounding ~1e-3 each.
constexpr int G = 24;
constexpr int NCELL_PAD = 14336;      // 1024*14 >= 24^3 = 13824
constexpr int CPT = NCELL_PAD / 1024; // 14 cells per thread in build
constexpr float GRID_LO = -4.0f;
constexpr float INV_H = 3.0f;         // 1/h
constexpr float H_CELL = 1.0f / 3.0f;

constexpr size_t PTS_OFF = 65536;     // off int[14337] in [0,57348); pts after
constexpr size_t WS_NEED = PTS_OFF + (size_t)N_SRC * sizeof(float4);

__device__ __forceinline__ int cell_of(float x) {
    int c = (int)((x - GRID_LO) * INV_H);   // trunc-vs-floor masked by clamp
    return min(max(c, 0), G - 1);
}

// ONE block, 1024 threads: zero -> LDS histogram -> scan -> scatter + offsets.
__global__ __launch_bounds__(1024) void build_grid(const float* __restrict__ src,
                                                   int* __restrict__ off,
                                                   float4* __restrict__ pts,
                                                   float* __restrict__ out) {
    __shared__ int cnt[NCELL_PAD];   // 56 KB
    __shared__ int aux[1024];        // 4 KB
    const int tid = threadIdx.x;
    if (tid == 0) out[0] = 0.0f;     // d_out poisoned 0xAA each launch

#pragma unroll
    for (int k = 0; k < CPT; ++k) cnt[tid + k * 1024] = 0;
    __syncthreads();

#pragma unroll
    for (int k = 0; k < N_SRC / 1024; ++k) {   // histogram
        int j = tid + k * 1024;
        float x = src[3 * j], y = src[3 * j + 1], z = src[3 * j + 2];
        int cid = (cell_of(z) * G + cell_of(y)) * G + cell_of(x);
        atomicAdd(&cnt[cid], 1);
    }
    __syncthreads();

    // exclusive scan: serial-14 per thread, Hillis-Steele over 1024 partials
    int run = 0;
    const int bc = tid * CPT;
#pragma unroll
    for (int k = 0; k < CPT; ++k) { int c = cnt[bc + k]; cnt[bc + k] = run; run += c; }
    aux[tid] = run;
    __syncthreads();
    for (int d = 1; d < 1024; d <<= 1) {
        int v = (tid >= d) ? aux[tid - d] : 0;
        __syncthreads();
        aux[tid] += v;
        __syncthreads();
    }
    const int base = aux[tid] - run;   // exclusive block base
#pragma unroll
    for (int k = 0; k < CPT; ++k) {    // finalize cursors + global offsets
        int v = cnt[bc + k] + base;
        cnt[bc + k] = v;
        off[bc + k] = v;
    }
    if (tid == 0) off[NCELL_PAD] = N_SRC;
    __syncthreads();

#pragma unroll
    for (int k = 0; k < N_SRC / 1024; ++k) {   // scatter
        int j = tid + k * 1024;
        float x = src[3 * j], y = src[3 * j + 1], z = src[3 * j + 2];
        int cid = (cell_of(z) * G + cell_of(y)) * G + cell_of(x);
        int pos = atomicAdd(&cnt[cid], 1);
        pts[pos] = make_float4(x, y, z, 0.0f);
    }
}

// One WAVE per target (wave-uniform shell loop; 64-lane point parallelism).
__global__ __launch_bounds__(256) void query_grid(const float* __restrict__ tar,
                                                  const int* __restrict__ off,
                                                  const float4* __restrict__ pts,
                                                  float* __restrict__ out) {
    const int tid  = threadIdx.x;
    const int lane = tid & 63;
    const int wv   = tid >> 6;             // 0..3
    const int t    = blockIdx.x * 4 + wv;  // target per wave

    const float qx = tar[3 * t], qy = tar[3 * t + 1], qz = tar[3 * t + 2];
    const int qcx = cell_of(qx), qcy = cell_of(qy), qcz = cell_of(qz);

    float bd2 = INFINITY;
    float gb  = INFINITY;

    auto visit = [&](int cx, int cy, int cz) {
        int cid = __builtin_amdgcn_readfirstlane((cz * G + cy) * G + cx);
        int beg = off[cid];       // scalar loads (SGPR index)
        int end = off[cid + 1];
        for (int p = beg + lane; p < end; p += 64) {
            float4 q = pts[p];    // 64 consecutive float4 = coalesced, L2-hot
            float dx = q.x - qx, dy = q.y - qy, dz = q.z - qz;
            float d2 = fmaf(dx, dx, fmaf(dy, dy, dz * dz));  // EXACT loss d2
            bd2 = fminf(bd2, d2);
        }
    };

    for (int s = 0; s < G; ++s) {          // shells; s=G-1 covers whole grid
        int z0 = max(qcz - s, 0), z1 = min(qcz + s, G - 1);
        int y0 = max(qcy - s, 0), y1 = min(qcy + s, G - 1);
        int x0 = max(qcx - s, 0), x1 = min(qcx + s, G - 1);
        for (int cz = z0; cz <= z1; ++cz) {
            for (int cy = y0; cy <= y1; ++cy) {
                int dyz = max(abs(cz - qcz), abs(cy - qcy));
                if (dyz == s) {            // full x-row on shell surface
                    for (int cx = x0; cx <= x1; ++cx) visit(cx, cy, cz);
                } else {                   // only the two x-extremes
                    if (qcx - s >= 0)     visit(qcx - s, cy, cz);
                    if (qcx + s <= G - 1) visit(qcx + s, cy, cz);
                }
            }
        }
        gb = bd2;                          // wave-min for termination test
#pragma unroll
        for (int m = 1; m < 64; m <<= 1) gb = fminf(gb, __shfl_xor(gb, m, 64));
        float r = (float)s * H_CELL;       // lb of shell s+1 is s*h
        if (gb <= r * r) break;
    }

    __shared__ float part[4];
    if (lane == 0) part[wv] = 0.5f * gb;   // gb IS the exact loss term *2
    __syncthreads();
    if (tid == 0) atomicAdd(out, part[0] + part[1] + part[2] + part[3]);
}

// ---------------- fallback (ws too small): R6 kernel, proven 41 µs ----------
constexpr int FB_BLOCKS = M_TAR / 32;
constexpr int FB_TPB = 512;
constexpr int FB_CHUNKS = 128;
constexpr int FB_TILE = 4096;
constexpr int FB_TILES = N_SRC / FB_TILE;
constexpr int FB_BODIES = FB_TILE / FB_CHUNKS / 2;

__global__ void zero_out(float* __restrict__ out) {
    if (threadIdx.x == 0) out[0] = 0.0f;
}

__device__ __forceinline__ float embed_ao(float t, unsigned mask_v, unsigned row_s) {
    float r;
    asm("v_and_or_b32 %0, %1, %2, %3" : "=v"(r) : "v"(t), "v"(mask_v), "s"(row_s));
    return r;
}
__device__ __forceinline__ void min3(float& b, float e0, float e1) {
    asm("v_min3_f32 %0, %1, %2, %3" : "=v"(b) : "v"(b), "v"(e0), "v"(e1));
}

__global__ __launch_bounds__(FB_TPB, 4) void nn7(const float* __restrict__ src,
                                                 const float* __restrict__ tar,
                                                 float* __restrict__ out) {
    __shared__ float4 tile[FB_TILE];
    const int tid   = threadIdx.x;
    const int g     = tid & 3;
    const int chunk = tid >> 2;
    const int tbase = blockIdx.x * 32;
    float txm2[8], tym2[8], tzm2[8], best[8];
#pragma unroll
    for (int k = 0; k < 8; ++k) {
        int T = tbase + g + 4 * k;
        txm2[k] = -2.0f * tar[3 * T + 0];
        tym2[k] = -2.0f * tar[3 * T + 1];
        tzm2[k] = -2.0f * tar[3 * T + 2];
        best[k] = INFINITY;
    }
    unsigned mask_v = 0xFFFFFF80u;
    for (int tl = 0; tl < FB_TILES; ++tl) {
#pragma unroll
        for (int r = 0; r < FB_TILE / FB_TPB; ++r) {
            int p  = tid + r * FB_TPB;
            int j3 = 3 * (tl * FB_TILE + p);
            float x = src[j3 + 0], y = src[j3 + 1], z = src[j3 + 2];
            tile[p] = make_float4(x, y, z, fmaf(x, x, fmaf(y, y, z * z)));
        }
        __syncthreads();
#pragma unroll
        for (int i = 0; i < FB_BODIES; ++i) {
            float4 s0 = tile[(2 * i + 0) * FB_CHUNKS + chunk];
            float4 s1 = tile[(2 * i + 1) * FB_CHUNKS + chunk];
            unsigned row0 = (unsigned)(tl * 2 * FB_BODIES + 2 * i);
            unsigned row1 = row0 + 1;
#pragma unroll
            for (int k = 0; k < 8; ++k) {
                float t0 = fmaf(s0.z, tzm2[k], s0.w);
                t0 = fmaf(s0.y, tym2[k], t0);
                t0 = fmaf(s0.x, txm2[k], t0);
                float t1 = fmaf(s1.z, tzm2[k], s1.w);
                t1 = fmaf(s1.y, tym2[k], t1);
                t1 = fmaf(s1.x, txm2[k], t1);
                float e0 = embed_ao(t0, mask_v, row0);
                float e1 = embed_ao(t1, mask_v, row1);
                min3(best[k], e0, e1);
            }
        }
        __syncthreads();
    }
    float* fv = (float*)tile;
    int*   fj = (int*)tile + 32 * 128;
#pragma unroll
    for (int k = 0; k < 8; ++k) {
        unsigned b = __float_as_uint(best[k]);
        int j  = (int)((b & 127u) * FB_CHUNKS + chunk);
        int lt = g + 4 * k;
        fv[lt * FB_CHUNKS + chunk] = __uint_as_float(b & 0xFFFFFF80u);
        fj[lt * FB_CHUNKS + chunk] = j;
    }
    __syncthreads();
    const int tprime = tid >> 4;
    const int sub    = tid & 15;
    float bv = fv[tprime * FB_CHUNKS + sub];
    int   bj = fj[tprime * FB_CHUNKS + sub];
#pragma unroll
    for (int m = 1; m < 8; ++m) {
        float v = fv[tprime * FB_CHUNKS + sub + 16 * m];
        int   j = fj[tprime * FB_CHUNKS + sub + 16 * m];
        if (v < bv) { bv = v; bj = j; }
    }
#pragma unroll
    for (int s = 8; s >= 1; s >>= 1) {
        float vv = __shfl_xor(bv, s, 64);
        int   jj = __shfl_xor(bj, s, 64);
        if (vv < bv) { bv = vv; bj = jj; }
    }
    __syncthreads();
    if (sub == 0) {
        int tt = tbase + tprime;
        float dx = src[3 * bj + 0] - tar[3 * tt + 0];
        float dy = src[3 * bj + 1] - tar[3 * tt + 1];
        float dz = src[3 * bj + 2] - tar[3 * tt + 2];
        fv[tprime] = 0.5f * fmaf(dx, dx, fmaf(dy, dy, dz * dz));
    }
    __syncthreads();
    if (tid == 0) {
        float ssum = 0.0f;
#pragma unroll
        for (int i = 0; i < 32; ++i) ssum += fv[i];
        atomicAdd(out, ssum);
    }
}

extern "C" void kernel_launch(void* const* d_in, const int* in_sizes, int n_in,
                              void* d_out, int out_size, void* d_ws, size_t ws_size,
                              hipStream_t stream) {
    const float* src = (const float*)d_in[0];  // src_V [N,3] fp32
    const float* tar = (const float*)d_in[1];  // tar_V [M,3] fp32
    float* out = (float*)d_out;                // scalar loss fp32

    if (ws_size >= WS_NEED) {
        int*    off = (int*)d_ws;
        float4* pts = (float4*)((char*)d_ws + PTS_OFF);
        build_grid<<<1, 1024, 0, stream>>>(src, off, pts, out);
        query_grid<<<M_TAR / 4, 256, 0, stream>>>(tar, off, pts, out);
    } else {
        zero_out<<<1, 64, 0, stream>>>(out);
        nn7<<<FB_BLOCKS, FB_TPB, 0, stream>>>(src, tar, out);
    }
}

// Round 10
// 144.608 us; speedup vs baseline: 1.2949x; 1.2949x over previous
//
#include <hip/hip_runtime.h>
#include <math.h>

// Problem constants (fixed by setup_inputs): N src points, M targets, D=3.
constexpr int N_SRC = 16384;
constexpr int M_TAR = 16384;

// ---------------- R10: uniform-grid exact 1-NN, parallelized ----------------
// Grid 24^3 over [-4,4), h=1/3; outliers clamp to edge cells (lb math stays
// valid from any true query position). Loss needs only min EXACT fp32 d2.
// R9 lesson: serial per-cell visits = 2 dependent L2 latencies/cell + corner
// tail walking many shells. Fix: (a) x-adjacent cells are CONTIGUOUS in the
// sorted array -> (2s+1)^3 cube = (2s+1)^2 ranges, metadata fetched by
// lane-per-range in ONE latency, drained via register broadcasts;
// (b) cube sizes s=1,2 then bounded brute-force fallback (~0.7% of waves).
constexpr int G = 24;
constexpr int NCELL = G * G * G;        // 13824
constexpr int NCELL_PAD = 14336;        // 1024*14
constexpr int CPT = NCELL_PAD / 1024;   // 14
constexpr float GRID_LO = -4.0f;
constexpr float INV_H = 3.0f;
constexpr float H_CELL = 1.0f / 3.0f;

// ws layout: off int[14337] @0 ; cnt/cursor int[14336] @65536 ; pts @131072
constexpr size_t CNT_OFF = 65536;
constexpr size_t PTS_OFF = 131072;
constexpr size_t WS_NEED = PTS_OFF + (size_t)N_SRC * sizeof(float4);

__device__ __forceinline__ int cell_of(float x) {
    int c = (int)((x - GRID_LO) * INV_H);
    return min(max(c, 0), G - 1);
}

// 64 blocks x 256: one point each, histogram via device-scope atomics.
__global__ __launch_bounds__(256) void hist_k(const float* __restrict__ src,
                                              int* __restrict__ cnt) {
    int j = blockIdx.x * 256 + threadIdx.x;
    float x = src[3 * j], y = src[3 * j + 1], z = src[3 * j + 2];
    int cid = (cell_of(z) * G + cell_of(y)) * G + cell_of(x);
    atomicAdd(&cnt[cid], 1);
}

// 1 block x 1024: exclusive scan of cnt -> off, cursor := off, out := 0.
__global__ __launch_bounds__(1024) void scan_k(int* __restrict__ cnt,
                                               int* __restrict__ off,
                                               float* __restrict__ out) {
    __shared__ int aux[1024];
    const int tid = threadIdx.x;
    if (tid == 0) out[0] = 0.0f;   // d_out poisoned 0xAA each launch
    const int bc = tid * CPT;
    int c[CPT];
#pragma unroll
    for (int k = 0; k < CPT; ++k) c[k] = cnt[bc + k];
    int run = 0;
#pragma unroll
    for (int k = 0; k < CPT; ++k) { int v = c[k]; c[k] = run; run += v; }
    aux[tid] = run;
    __syncthreads();
    for (int d = 1; d < 1024; d <<= 1) {
        int v = (tid >= d) ? aux[tid - d] : 0;
        __syncthreads();
        aux[tid] += v;
        __syncthreads();
    }
    const int base = aux[tid] - run;
#pragma unroll
    for (int k = 0; k < CPT; ++k) {
        int v = c[k] + base;
        off[bc + k] = v;
        cnt[bc + k] = v;      // becomes the scatter cursor
    }
    if (tid == 0) off[NCELL_PAD] = N_SRC;
}

// 64 blocks x 256: scatter points into cell-sorted order.
__global__ __launch_bounds__(256) void scatter_k(const float* __restrict__ src,
                                                 int* __restrict__ cursor,
                                                 float4* __restrict__ pts) {
    int j = blockIdx.x * 256 + threadIdx.x;
    float x = src[3 * j], y = src[3 * j + 1], z = src[3 * j + 2];
    int cid = (cell_of(z) * G + cell_of(y)) * G + cell_of(x);
    int pos = atomicAdd(&cursor[cid], 1);
    pts[pos] = make_float4(x, y, z, 0.0f);
}

// One WAVE per target. Stages s=1 (27 cells as 9 x-contiguous ranges) and
// s=2 (125 cells as 25 ranges), then brute-force fallback for survivors.
__global__ __launch_bounds__(256) void query2(const float* __restrict__ tar,
                                              const int* __restrict__ off,
                                              const float4* __restrict__ pts,
                                              float* __restrict__ out) {
    const int tid  = threadIdx.x;
    const int lane = tid & 63;
    const int wv   = tid >> 6;
    const int t    = blockIdx.x * 4 + wv;

    const float qx = tar[3 * t], qy = tar[3 * t + 1], qz = tar[3 * t + 2];
    const int qcx = cell_of(qx), qcy = cell_of(qy), qcz = cell_of(qz);

    float bd2 = INFINITY;
    bool done = false;

    for (int s = 1; s <= 2; ++s) {         // wave-uniform stage loop
        const int W = 2 * s + 1, R = W * W;
        // lane-per-range metadata fetch (ONE parallel latency)
        int beg = 0, cnt = 0;
        if (lane < R) {
            int cy = qcy + (lane % W) - s;
            int cz = qcz + (lane / W) - s;
            if (cy >= 0 && cy < G && cz >= 0 && cz < G) {
                int x0 = max(qcx - s, 0), x1 = min(qcx + s, G - 1);
                int rowb = (cz * G + cy) * G;
                int b = off[rowb + x0];
                int e = off[rowb + x1 + 1];   // x-contiguous cells = one range
                beg = b; cnt = e - b;
            }
        }
        // drain ranges: register broadcast (readlane), all 64 lanes load pts
        for (int k = 0; k < R; ++k) {
            int ck = __shfl(cnt, k, 64);      // uniform k -> v_readlane
            if (ck == 0) continue;            // uniform skip
            int bk = __shfl(beg, k, 64);
            for (int p = lane; p < ck; p += 64) {
                float4 q = pts[bk + p];       // coalesced, L2-hot
                float dx = q.x - qx, dy = q.y - qy, dz = q.z - qz;
                bd2 = fminf(bd2, fmaf(dx, dx, fmaf(dy, dy, dz * dz)));
            }
        }
        float gb = bd2;                       // wave-uniform min
#pragma unroll
        for (int m = 1; m < 64; m <<= 1) gb = fminf(gb, __shfl_xor(gb, m, 64));
        bd2 = gb;
        float r = (float)s * H_CELL;          // outside-cube lb = s*h
        if (gb <= r * r) { done = true; break; }
    }

    if (!done) {                              // ~0.7% of waves: exact fallback
        for (int p = lane; p < N_SRC; p += 64) {
            float4 q = pts[p];
            float dx = q.x - qx, dy = q.y - qy, dz = q.z - qz;
            bd2 = fminf(bd2, fmaf(dx, dx, fmaf(dy, dy, dz * dz)));
        }
#pragma unroll
        for (int m = 1; m < 64; m <<= 1) bd2 = fminf(bd2, __shfl_xor(bd2, m, 64));
    }

    __shared__ float part[4];
    if (lane == 0) part[wv] = 0.5f * bd2;     // exact loss term
    __syncthreads();
    if (tid == 0) atomicAdd(out, part[0] + part[1] + part[2] + part[3]);
}

// ---------------- fallback (ws too small): R6 kernel, proven 41 µs ----------
constexpr int FB_BLOCKS = M_TAR / 32;
constexpr int FB_TPB = 512;
constexpr int FB_CHUNKS = 128;
constexpr int FB_TILE = 4096;
constexpr int FB_TILES = N_SRC / FB_TILE;
constexpr int FB_BODIES = FB_TILE / FB_CHUNKS / 2;

__global__ void zero_out(float* __restrict__ out) {
    if (threadIdx.x == 0) out[0] = 0.0f;
}

__device__ __forceinline__ float embed_ao(float t, unsigned mask_v, unsigned row_s) {
    float r;
    asm("v_and_or_b32 %0, %1, %2, %3" : "=v"(r) : "v"(t), "v"(mask_v), "s"(row_s));
    return r;
}
__device__ __forceinline__ void min3(float& b, float e0, float e1) {
    asm("v_min3_f32 %0, %1, %2, %3" : "=v"(b) : "v"(b), "v"(e0), "v"(e1));
}

__global__ __launch_bounds__(FB_TPB, 4) void nn7(const float* __restrict__ src,
                                                 const float* __restrict__ tar,
                                                 float* __restrict__ out) {
    __shared__ float4 tile[FB_TILE];
    const int tid   = threadIdx.x;
    const int g     = tid & 3;
    const int chunk = tid >> 2;
    const int tbase = blockIdx.x * 32;
    float txm2[8], tym2[8], tzm2[8], best[8];
#pragma unroll
    for (int k = 0; k < 8; ++k) {
        int T = tbase + g + 4 * k;
        txm2[k] = -2.0f * tar[3 * T + 0];
        tym2[k] = -2.0f * tar[3 * T + 1];
        tzm2[k] = -2.0f * tar[3 * T + 2];
        best[k] = INFINITY;
    }
    unsigned mask_v = 0xFFFFFF80u;
    for (int tl = 0; tl < FB_TILES; ++tl) {
#pragma unroll
        for (int r = 0; r < FB_TILE / FB_TPB; ++r) {
            int p  = tid + r * FB_TPB;
            int j3 = 3 * (tl * FB_TILE + p);
            float x = src[j3 + 0], y = src[j3 + 1], z = src[j3 + 2];
            tile[p] = make_float4(x, y, z, fmaf(x, x, fmaf(y, y, z * z)));
        }
        __syncthreads();
#pragma unroll
        for (int i = 0; i < FB_BODIES; ++i) {
            float4 s0 = tile[(2 * i + 0) * FB_CHUNKS + chunk];
            float4 s1 = tile[(2 * i + 1) * FB_CHUNKS + chunk];
            unsigned row0 = (unsigned)(tl * 2 * FB_BODIES + 2 * i);
            unsigned row1 = row0 + 1;
#pragma unroll
            for (int k = 0; k < 8; ++k) {
                float t0 = fmaf(s0.z, tzm2[k], s0.w);
                t0 = fmaf(s0.y, tym2[k], t0);
                t0 = fmaf(s0.x, txm2[k], t0);
                float t1 = fmaf(s1.z, tzm2[k], s1.w);
                t1 = fmaf(s1.y, tym2[k], t1);
                t1 = fmaf(s1.x, txm2[k], t1);
                float e0 = embed_ao(t0, mask_v, row0);
                float e1 = embed_ao(t1, mask_v, row1);
                min3(best[k], e0, e1);
            }
        }
        __syncthreads();
    }
    float* fv = (float*)tile;
    int*   fj = (int*)tile + 32 * 128;
#pragma unroll
    for (int k = 0; k < 8; ++k) {
        unsigned b = __float_as_uint(best[k]);
        int j  = (int)((b & 127u) * FB_CHUNKS + chunk);
        int lt = g + 4 * k;
        fv[lt * FB_CHUNKS + chunk] = __uint_as_float(b & 0xFFFFFF80u);
        fj[lt * FB_CHUNKS + chunk] = j;
    }
    __syncthreads();
    const int tprime = tid >> 4;
    const int sub    = tid & 15;
    float bv = fv[tprime * FB_CHUNKS + sub];
    int   bj = fj[tprime * FB_CHUNKS + sub];
#pragma unroll
    for (int m = 1; m < 8; ++m) {
        float v = fv[tprime * FB_CHUNKS + sub + 16 * m];
        int   j = fj[tprime * FB_CHUNKS + sub + 16 * m];
        if (v < bv) { bv = v; bj = j; }
    }
#pragma unroll
    for (int s = 8; s >= 1; s >>= 1) {
        float vv = __shfl_xor(bv, s, 64);
        int   jj = __shfl_xor(bj, s, 64);
        if (vv < bv) { bv = vv; bj = jj; }
    }
    __syncthreads();
    if (sub == 0) {
        int tt = tbase + tprime;
        float dx = src[3 * bj + 0] - tar[3 * tt + 0];
        float dy = src[3 * bj + 1] - tar[3 * tt + 1];
        float dz = src[3 * bj + 2] - tar[3 * tt + 2];
        fv[tprime] = 0.5f * fmaf(dx, dx, fmaf(dy, dy, dz * dz));
    }
    __syncthreads();
    if (tid == 0) {
        float ssum = 0.0f;
#pragma unroll
        for (int i = 0; i < 32; ++i) ssum += fv[i];
        atomicAdd(out, ssum);
    }
}

extern "C" void kernel_launch(void* const* d_in, const int* in_sizes, int n_in,
                              void* d_out, int out_size, void* d_ws, size_t ws_size,
                              hipStream_t stream) {
    const float* src = (const float*)d_in[0];  // src_V [N,3] fp32
    const float* tar = (const float*)d_in[1];  // tar_V [M,3] fp32
    float* out = (float*)d_out;                // scalar loss fp32

    if (ws_size >= WS_NEED) {
        int*    off = (int*)d_ws;
        int*    cnt = (int*)((char*)d_ws + CNT_OFF);   // then cursor
        float4* pts = (float4*)((char*)d_ws + PTS_OFF);
        hipMemsetAsync(cnt, 0, NCELL_PAD * sizeof(int), stream);
        hist_k<<<N_SRC / 256, 256, 0, stream>>>(src, cnt);
        scan_k<<<1, 1024, 0, stream>>>(cnt, off, out);
        scatter_k<<<N_SRC / 256, 256, 0, stream>>>(src, cnt, pts);
        query2<<<M_TAR / 4, 256, 0, stream>>>(tar, off, pts, out);
    } else {
        zero_out<<<1, 64, 0, stream>>>(out);
        nn7<<<FB_BLOCKS, FB_TPB, 0, stream>>>(src, tar, out);
    }
}